// Round 1
// baseline (1136.907 us; speedup 1.0000x reference)
//
#include <hip/hip_runtime.h>
#include <hip/hip_bf16.h>
#include <math.h>

// Problem constants (structure of the model; N/E derived at runtime)
#define NPG   100
#define FIN   128
#define KK    30
#define NC    10
#define FC    97   // concat feature width: 32+32+32+1

// ---------------- CSR build ----------------

__global__ void count_deg(const int* __restrict__ dst, int* __restrict__ cnt, int E) {
    int e = blockIdx.x * 256 + threadIdx.x;
    if (e < E) atomicAdd(&cnt[dst[e]], 1);
}

__global__ void make_dinv(const int* __restrict__ cnt, float* __restrict__ dinv, int N) {
    int n = blockIdx.x * 256 + threadIdx.x;
    if (n < N) dinv[n] = rsqrtf((float)cnt[n] + 1.0f);
}

// single-block exclusive scan of cnt -> off (off[N] = total)
__global__ void scan_off(const int* __restrict__ cnt, int* __restrict__ off, int N) {
    __shared__ int ps[1024];
    int t = threadIdx.x;
    int chunk = (N + 1023) >> 10;
    int lo = t * chunk;
    int hi = lo + chunk; if (hi > N) hi = N; if (lo > N) lo = N;
    int s = 0;
    for (int i = lo; i < hi; ++i) s += cnt[i];
    ps[t] = s;
    __syncthreads();
    // Hillis-Steele inclusive scan
    for (int d = 1; d < 1024; d <<= 1) {
        int val = (t >= d) ? ps[t - d] : 0;
        __syncthreads();
        ps[t] += val;
        __syncthreads();
    }
    int base = (t == 0) ? 0 : ps[t - 1];
    for (int i = lo; i < hi; ++i) { off[i] = base; base += cnt[i]; }
    if (t == 1023) off[N] = ps[1023];
}

// bucket src ids by dst
__global__ void fill_csr(const int* __restrict__ src, const int* __restrict__ dst,
                         const int* __restrict__ off, int* __restrict__ cur,
                         int* __restrict__ eby, int E) {
    int e = blockIdx.x * 256 + threadIdx.x;
    if (e >= E) return;
    int d = dst[e];
    int p = atomicAdd(&cur[d], 1);
    eby[off[d] + p] = src[e];
}

// ---------------- GEMMs ----------------

// h[N][32] = x[N][128] @ W[128][32]
__global__ void gemm128_32(const float* __restrict__ x, const float* __restrict__ W,
                           float* __restrict__ h, int N) {
    __shared__ float Ws[128 * 32];
    int t = threadIdx.x;
    for (int i = t; i < 128 * 32; i += 256) Ws[i] = W[i];
    __syncthreads();
    int idx = blockIdx.x * 256 + t;
    int n = idx >> 5, c = idx & 31;
    if (n >= N) return;
    const float4* x4 = (const float4*)(x + (size_t)n * 128);
    float a = 0.f;
#pragma unroll
    for (int k4 = 0; k4 < 32; ++k4) {
        float4 xv = x4[k4];
        int k = k4 * 4;
        a += xv.x * Ws[k * 32 + c];
        a += xv.y * Ws[(k + 1) * 32 + c];
        a += xv.z * Ws[(k + 2) * 32 + c];
        a += xv.w * Ws[(k + 3) * 32 + c];
    }
    h[(size_t)n * 32 + c] = a;
}

// h[N][32] = xc[:, colOff:colOff+32] @ W[32][32]   (xc row stride FC)
__global__ void gemm32_32(const float* __restrict__ xc, int colOff,
                          const float* __restrict__ W, float* __restrict__ h, int N) {
    __shared__ float Ws[32 * 32];
    int t = threadIdx.x;
    for (int i = t; i < 32 * 32; i += 256) Ws[i] = W[i];
    __syncthreads();
    int idx = blockIdx.x * 256 + t;
    int n = idx >> 5, c = idx & 31;
    if (n >= N) return;
    const float* xr = xc + (size_t)n * FC + colOff;
    float a = 0.f;
#pragma unroll
    for (int k = 0; k < 32; ++k) a += xr[k] * Ws[k * 32 + c];
    h[(size_t)n * 32 + c] = a;
}

// hv[N] = xc[:, colOff:colOff+32] @ W4[32]
__global__ void gemm32_1(const float* __restrict__ xc, int colOff,
                         const float* __restrict__ W4, float* __restrict__ hv, int N) {
    int n = blockIdx.x * 256 + threadIdx.x;
    if (n >= N) return;
    const float* xr = xc + (size_t)n * FC + colOff;
    float a = 0.f;
#pragma unroll
    for (int k = 0; k < 32; ++k) a += xr[k] * W4[k];
    hv[n] = a;
}

// ---------------- aggregation (gather, no atomics) ----------------

// out = tanh( dinv[n] * ( h[n][c]*dinv[n] + sum_{s in N(n)} h[s][c]*dinv[s] ) + b[c] )
__global__ void agg32(const float* __restrict__ h, const int* __restrict__ off,
                      const int* __restrict__ eby, const float* __restrict__ dinv,
                      const float* __restrict__ b, float* __restrict__ xc, int colOff, int N) {
    int idx = blockIdx.x * 256 + threadIdx.x;
    int n = idx >> 5, c = idx & 31;
    if (n >= N) return;
    float dn = dinv[n];
    float acc = h[(size_t)n * 32 + c] * dn;
    int e0 = off[n], e1 = off[n + 1];
    for (int j = e0; j < e1; ++j) {
        int s = eby[j];
        acc += h[(size_t)s * 32 + c] * dinv[s];
    }
    xc[(size_t)n * FC + colOff + c] = tanhf(acc * dn + b[c]);
}

__global__ void agg1(const float* __restrict__ hv, const int* __restrict__ off,
                     const int* __restrict__ eby, const float* __restrict__ dinv,
                     const float* __restrict__ b4, float* __restrict__ xc, int N) {
    int n = blockIdx.x * 256 + threadIdx.x;
    if (n >= N) return;
    float dn = dinv[n];
    float acc = hv[n] * dn;
    int e0 = off[n], e1 = off[n + 1];
    for (int j = e0; j < e1; ++j) {
        int s = eby[j];
        acc += hv[s] * dinv[s];
    }
    xc[(size_t)n * FC + 96] = tanhf(acc * dn + b4[0]);
}

// ---------------- fused head: sort-pool + conv + pool + conv + fc + log_softmax ----------------

__global__ void head_kernel(const float* __restrict__ xc,
                            const float* __restrict__ c5w, const float* __restrict__ c5b,
                            const float* __restrict__ c6w, const float* __restrict__ c6b,
                            const float* __restrict__ f1w, const float* __restrict__ f1b,
                            const float* __restrict__ f2w, const float* __restrict__ f2b,
                            float* __restrict__ out) {
    __shared__ float v[NPG];
    __shared__ int   ord[KK];
    __shared__ float topk[KK * FC];   // 2910
    __shared__ float o5[16 * 30];
    __shared__ float p5[16 * 15];
    __shared__ float z[352];
    __shared__ float h1[128];
    __shared__ float lg[NC];
    __shared__ float lse;

    int g = blockIdx.x;
    int t = threadIdx.x;
    const float* xg = xc + (size_t)g * NPG * FC;

    if (t < NPG) v[t] = xg[t * FC + 96];
    __syncthreads();
    if (t < NPG) {
        float vi = v[t];
        int r = 0;
        for (int j = 0; j < NPG; ++j) {
            float vj = v[j];
            r += (vj > vi) || (vj == vi && j < t);  // stable descending rank
        }
        if (r < KK) ord[r] = t;
    }
    __syncthreads();
    for (int i = t; i < KK * FC; i += 128) {
        int r = i / FC, f = i - r * FC;
        topk[i] = xg[ord[r] * FC + f];
    }
    __syncthreads();
    // conv1d(1,16,97,stride 97) + relu : 16 x 30 outputs
    for (int i = t; i < 16 * 30; i += 128) {
        int ch = i / 30, tt = i - ch * 30;
        float a = c5b[ch];
        const float* w = c5w + ch * FC;
        const float* xx = topk + tt * FC;
        for (int f = 0; f < FC; ++f) a += xx[f] * w[f];
        o5[ch * 30 + tt] = fmaxf(a, 0.f);
    }
    __syncthreads();
    // maxpool k2 s2 : 16 x 15
    for (int i = t; i < 16 * 15; i += 128) {
        int ch = i / 15, tt = i - ch * 15;
        p5[i] = fmaxf(o5[ch * 30 + 2 * tt], o5[ch * 30 + 2 * tt + 1]);
    }
    __syncthreads();
    // conv1d(16,32,5) + relu : 32 x 11 -> z[352]
    for (int i = t; i < 32 * 11; i += 128) {
        int oc = i / 11, tt = i - oc * 11;
        float a = c6b[oc];
#pragma unroll
        for (int ic = 0; ic < 16; ++ic) {
#pragma unroll
            for (int k = 0; k < 5; ++k)
                a += p5[ic * 15 + tt + k] * c6w[oc * 80 + ic * 5 + k];
        }
        z[oc * 11 + tt] = fmaxf(a, 0.f);
    }
    __syncthreads();
    // fc1: 352 -> 128, relu (one output per thread)
    {
        float a = f1b[t];
        for (int i = 0; i < 352; ++i) a += z[i] * f1w[i * 128 + t];
        h1[t] = fmaxf(a, 0.f);
    }
    __syncthreads();
    // fc2: 128 -> 10
    if (t < NC) {
        float a = f2b[t];
#pragma unroll
        for (int j = 0; j < 128; ++j) a += h1[j] * f2w[j * NC + t];
        lg[t] = a;
    }
    __syncthreads();
    if (t == 0) {
        float m = lg[0];
        for (int c = 1; c < NC; ++c) m = fmaxf(m, lg[c]);
        float s = 0.f;
        for (int c = 0; c < NC; ++c) s += expf(lg[c] - m);
        lse = m + logf(s);
    }
    __syncthreads();
    if (t < NC) out[(size_t)g * NC + t] = lg[t] - lse;
}

// ---------------- launch ----------------

static inline size_t align_up(size_t x, size_t a) { return (x + a - 1) & ~(a - 1); }

extern "C" void kernel_launch(void* const* d_in, const int* in_sizes, int n_in,
                              void* d_out, int out_size, void* d_ws, size_t ws_size,
                              hipStream_t stream) {
    const float* x   = (const float*)d_in[0];
    const int*   ei  = (const int*)d_in[1];
    // d_in[2] = batch (uniform, unused)
    const float* W1  = (const float*)d_in[3];
    const float* b1  = (const float*)d_in[4];
    const float* W2  = (const float*)d_in[5];
    const float* b2  = (const float*)d_in[6];
    const float* W3  = (const float*)d_in[7];
    const float* b3  = (const float*)d_in[8];
    const float* W4  = (const float*)d_in[9];
    const float* b4  = (const float*)d_in[10];
    const float* c5w = (const float*)d_in[11];
    const float* c5b = (const float*)d_in[12];
    const float* c6w = (const float*)d_in[13];
    const float* c6b = (const float*)d_in[14];
    const float* f1w = (const float*)d_in[15];
    const float* f1b = (const float*)d_in[16];
    const float* f2w = (const float*)d_in[17];
    const float* f2b = (const float*)d_in[18];
    float* out = (float*)d_out;

    const int N = in_sizes[0] / FIN;
    const int E = in_sizes[1] / 2;
    const int G = N / NPG;
    const int* src = ei;
    const int* dst = ei + E;

    char* ws = (char*)d_ws;
    size_t o = 0;
    int*   cnt  = (int*)(ws + o);  o = align_up(o + (size_t)N * 4, 256);
    float* dinv = (float*)(ws + o); o = align_up(o + (size_t)N * 4, 256);
    int*   off  = (int*)(ws + o);  o = align_up(o + (size_t)(N + 1) * 4, 256);
    int*   cur  = (int*)(ws + o);  o = align_up(o + (size_t)N * 4, 256);
    int*   eby  = (int*)(ws + o);  o = align_up(o + (size_t)E * 4, 256);
    float* h    = (float*)(ws + o); o = align_up(o + (size_t)N * 32 * 4, 256);
    float* xcb  = (float*)(ws + o); o = align_up(o + (size_t)N * FC * 4, 256);
    (void)ws_size;

    hipMemsetAsync(cnt, 0, (size_t)N * 4, stream);
    hipMemsetAsync(cur, 0, (size_t)N * 4, stream);

    int gbE  = (E + 255) / 256;
    int gbN  = (N + 255) / 256;
    int gbNC = ((size_t)N * 32 + 255) / 256;

    count_deg<<<gbE, 256, 0, stream>>>(dst, cnt, E);
    make_dinv<<<gbN, 256, 0, stream>>>(cnt, dinv, N);
    scan_off<<<1, 1024, 0, stream>>>(cnt, off, N);
    fill_csr<<<gbE, 256, 0, stream>>>(src, dst, off, cur, eby, E);

    // layer 1: 128 -> 32
    gemm128_32<<<gbNC, 256, 0, stream>>>(x, W1, h, N);
    agg32<<<gbNC, 256, 0, stream>>>(h, off, eby, dinv, b1, xcb, 0, N);
    // layer 2: 32 -> 32
    gemm32_32<<<gbNC, 256, 0, stream>>>(xcb, 0, W2, h, N);
    agg32<<<gbNC, 256, 0, stream>>>(h, off, eby, dinv, b2, xcb, 32, N);
    // layer 3: 32 -> 32
    gemm32_32<<<gbNC, 256, 0, stream>>>(xcb, 32, W3, h, N);
    agg32<<<gbNC, 256, 0, stream>>>(h, off, eby, dinv, b3, xcb, 64, N);
    // layer 4: 32 -> 1
    gemm32_1<<<gbN, 256, 0, stream>>>(xcb, 64, W4, h, N);
    agg1<<<gbN, 256, 0, stream>>>(h, off, eby, dinv, b4, xcb, N);

    // head
    head_kernel<<<G, 128, 0, stream>>>(xcb, c5w, c5b, c6w, c6b, f1w, f1b, f2w, f2b, out);
}

// Round 2
// 716.409 us; speedup vs baseline: 1.5870x; 1.5870x over previous
//
#include <hip/hip_runtime.h>
#include <hip/hip_bf16.h>
#include <math.h>

// Problem constants (structure of the model; N/E derived at runtime)
#define NPG   100
#define FIN   128
#define KK    30
#define NC    10
#define FC    97    // concat feature width: 32+32+32+1
#define XCS   100   // padded row stride for the concat buffer (16B-aligned rows)

#define BKT_SHIFT 6          // 64 nodes per bucket
#define NBMAX     2048       // supports N up to 131072 (also the src-packing limit 2^17)
#define CHA       8192       // edges per block in bucket pass A

__device__ inline void fma4(float4& a, float s, const float4& w) {
    a.x += s * w.x; a.y += s * w.y; a.z += s * w.z; a.w += s * w.w;
}

// ---------------- degree count / normalization ----------------

__global__ void count_deg(const int* __restrict__ dst, int* __restrict__ cnt, int E) {
    int e = blockIdx.x * 256 + threadIdx.x;
    if (e < E) atomicAdd(&cnt[dst[e]], 1);
}

__global__ void make_dinv(const int* __restrict__ cnt, float* __restrict__ dinv, int N) {
    int n = blockIdx.x * 256 + threadIdx.x;
    if (n < N) dinv[n] = rsqrtf((float)cnt[n] + 1.0f);
}

// single-block exclusive scan of cnt -> off (off[N] = total)
__global__ void scan_off(const int* __restrict__ cnt, int* __restrict__ off, int N) {
    __shared__ int ps[1024];
    int t = threadIdx.x;
    int chunk = (N + 1023) >> 10;
    int lo = t * chunk;
    int hi = lo + chunk; if (hi > N) hi = N; if (lo > N) lo = N;
    int s = 0;
    for (int i = lo; i < hi; ++i) s += cnt[i];
    ps[t] = s;
    __syncthreads();
    for (int d = 1; d < 1024; d <<= 1) {
        int val = (t >= d) ? ps[t - d] : 0;
        __syncthreads();
        ps[t] += val;
        __syncthreads();
    }
    int base = (t == 0) ? 0 : ps[t - 1];
    for (int i = lo; i < hi; ++i) { off[i] = base; base += cnt[i]; }
    if (t == 1023) off[N] = ps[1023];
}

// ---------------- CSR build: two-level bucket sort ----------------
// gcur[b] starts at off[b*64]; pass A appends packed (src | d_local<<17) per
// bucket with coalesced-ish writes; pass B (one workgroup per bucket) scatters
// src ids to final slots inside an ~8KB window resident in one XCD's L2.

__global__ void init_gcur(const int* __restrict__ off, int* __restrict__ gcur, int NB) {
    int b = blockIdx.x * 256 + threadIdx.x;
    if (b < NB) gcur[b] = off[b << BKT_SHIFT];
}

__global__ void bucketA(const int* __restrict__ src, const int* __restrict__ dst,
                        int* __restrict__ gcur, int* __restrict__ ebuf, int E, int NB) {
    __shared__ int hist[NBMAX];
    __shared__ int base[NBMAX];
    int t = threadIdx.x;
    int e0 = blockIdx.x * CHA;
    for (int i = t; i < NB; i += 256) hist[i] = 0;
    __syncthreads();
    for (int i = t; i < CHA; i += 256) {
        int e = e0 + i;
        if (e < E) atomicAdd(&hist[dst[e] >> BKT_SHIFT], 1);
    }
    __syncthreads();
    for (int i = t; i < NB; i += 256) {
        int h = hist[i];
        base[i] = h ? atomicAdd(&gcur[i], h) : 0;
        hist[i] = 0;
    }
    __syncthreads();
    for (int i = t; i < CHA; i += 256) {
        int e = e0 + i;
        if (e >= E) continue;
        int d = dst[e], b = d >> BKT_SHIFT;
        int r = atomicAdd(&hist[b], 1);
        ebuf[base[b] + r] = src[e] | ((d & 63) << 17);
    }
}

__global__ void bucketB(const int* __restrict__ ebuf, const int* __restrict__ off,
                        int* __restrict__ eby, int N) {
    __shared__ int lcur[64];
    int b = blockIdx.x;
    int n0 = b << BKT_SHIFT;
    int t = threadIdx.x;
    int nEnd = n0 + 64; if (nEnd > N) nEnd = N;
    if (t < 64 && n0 + t < N) lcur[t] = off[n0 + t];
    __syncthreads();
    int s = off[n0];
    int e = off[nEnd];
    for (int i = s + t; i < e; i += 256) {
        int v = ebuf[i];
        int pos = atomicAdd(&lcur[v >> 17], 1);
        eby[pos] = v & 0x1FFFF;
    }
}

// ---------------- GEMMs (register-blocked: 4 nodes x 4 ch / thread) ----------------

// h[N][32] = x[N][128] @ W[128][32]
__global__ void gemm128_32v(const float* __restrict__ x, const float* __restrict__ W,
                            float* __restrict__ h, int N) {
    __shared__ float Ws[128 * 32];
    int t = threadIdx.x;
    for (int i = t; i < 128 * 32; i += 256) Ws[i] = W[i];
    __syncthreads();
    int cg = (t & 7) * 4;
    int n0 = blockIdx.x * 128 + (t >> 3) * 4;
    if (n0 >= N) return;
    if (n0 + 4 <= N) {
        const float* xr = x + (size_t)n0 * 128;
        float4 a0 = {0,0,0,0}, a1 = a0, a2 = a0, a3 = a0;
#pragma unroll
        for (int k4 = 0; k4 < 32; ++k4) {
            float4 x0 = *(const float4*)(xr + k4 * 4);
            float4 x1 = *(const float4*)(xr + 128 + k4 * 4);
            float4 x2 = *(const float4*)(xr + 256 + k4 * 4);
            float4 x3 = *(const float4*)(xr + 384 + k4 * 4);
            float4 w0 = *(const float4*)&Ws[(4 * k4 + 0) * 32 + cg];
            float4 w1 = *(const float4*)&Ws[(4 * k4 + 1) * 32 + cg];
            float4 w2 = *(const float4*)&Ws[(4 * k4 + 2) * 32 + cg];
            float4 w3 = *(const float4*)&Ws[(4 * k4 + 3) * 32 + cg];
            fma4(a0, x0.x, w0); fma4(a0, x0.y, w1); fma4(a0, x0.z, w2); fma4(a0, x0.w, w3);
            fma4(a1, x1.x, w0); fma4(a1, x1.y, w1); fma4(a1, x1.z, w2); fma4(a1, x1.w, w3);
            fma4(a2, x2.x, w0); fma4(a2, x2.y, w1); fma4(a2, x2.z, w2); fma4(a2, x2.w, w3);
            fma4(a3, x3.x, w0); fma4(a3, x3.y, w1); fma4(a3, x3.z, w2); fma4(a3, x3.w, w3);
        }
        *(float4*)&h[(size_t)(n0 + 0) * 32 + cg] = a0;
        *(float4*)&h[(size_t)(n0 + 1) * 32 + cg] = a1;
        *(float4*)&h[(size_t)(n0 + 2) * 32 + cg] = a2;
        *(float4*)&h[(size_t)(n0 + 3) * 32 + cg] = a3;
    } else {
        for (int nn = 0; nn < 4; ++nn) {
            int n = n0 + nn; if (n >= N) break;
            float4 a = {0,0,0,0};
            for (int k = 0; k < 128; ++k)
                fma4(a, x[(size_t)n * 128 + k], *(const float4*)&Ws[k * 32 + cg]);
            *(float4*)&h[(size_t)n * 32 + cg] = a;
        }
    }
}

// h[N][32] = xc[:, colOff:colOff+32] @ W[32][32]   (xc row stride XCS)
__global__ void gemm32_32v(const float* __restrict__ xc, int colOff,
                           const float* __restrict__ W, float* __restrict__ h, int N) {
    __shared__ float Ws[32 * 32];
    int t = threadIdx.x;
    for (int i = t; i < 32 * 32; i += 256) Ws[i] = W[i];
    __syncthreads();
    int cg = (t & 7) * 4;
    int n0 = blockIdx.x * 128 + (t >> 3) * 4;
    if (n0 >= N) return;
    if (n0 + 4 <= N) {
        const float* xr = xc + (size_t)n0 * XCS + colOff;
        float4 a0 = {0,0,0,0}, a1 = a0, a2 = a0, a3 = a0;
#pragma unroll
        for (int k4 = 0; k4 < 8; ++k4) {
            float4 x0 = *(const float4*)(xr + k4 * 4);
            float4 x1 = *(const float4*)(xr + XCS + k4 * 4);
            float4 x2 = *(const float4*)(xr + 2 * XCS + k4 * 4);
            float4 x3 = *(const float4*)(xr + 3 * XCS + k4 * 4);
            float4 w0 = *(const float4*)&Ws[(4 * k4 + 0) * 32 + cg];
            float4 w1 = *(const float4*)&Ws[(4 * k4 + 1) * 32 + cg];
            float4 w2 = *(const float4*)&Ws[(4 * k4 + 2) * 32 + cg];
            float4 w3 = *(const float4*)&Ws[(4 * k4 + 3) * 32 + cg];
            fma4(a0, x0.x, w0); fma4(a0, x0.y, w1); fma4(a0, x0.z, w2); fma4(a0, x0.w, w3);
            fma4(a1, x1.x, w0); fma4(a1, x1.y, w1); fma4(a1, x1.z, w2); fma4(a1, x1.w, w3);
            fma4(a2, x2.x, w0); fma4(a2, x2.y, w1); fma4(a2, x2.z, w2); fma4(a2, x2.w, w3);
            fma4(a3, x3.x, w0); fma4(a3, x3.y, w1); fma4(a3, x3.z, w2); fma4(a3, x3.w, w3);
        }
        *(float4*)&h[(size_t)(n0 + 0) * 32 + cg] = a0;
        *(float4*)&h[(size_t)(n0 + 1) * 32 + cg] = a1;
        *(float4*)&h[(size_t)(n0 + 2) * 32 + cg] = a2;
        *(float4*)&h[(size_t)(n0 + 3) * 32 + cg] = a3;
    } else {
        for (int nn = 0; nn < 4; ++nn) {
            int n = n0 + nn; if (n >= N) break;
            float4 a = {0,0,0,0};
            for (int k = 0; k < 32; ++k)
                fma4(a, xc[(size_t)n * XCS + colOff + k], *(const float4*)&Ws[k * 32 + cg]);
            *(float4*)&h[(size_t)n * 32 + cg] = a;
        }
    }
}

// hv[N] = xc[:, colOff:colOff+32] @ W4[32]
__global__ void gemm32_1(const float* __restrict__ xc, int colOff,
                         const float* __restrict__ W4, float* __restrict__ hv, int N) {
    __shared__ float W4s[32];
    int t = threadIdx.x;
    if (t < 32) W4s[t] = W4[t];
    __syncthreads();
    int n = blockIdx.x * 256 + t;
    if (n >= N) return;
    const float* xr = xc + (size_t)n * XCS + colOff;
    float a = 0.f;
#pragma unroll
    for (int k4 = 0; k4 < 8; ++k4) {
        float4 xv = *(const float4*)(xr + k4 * 4);
        a += xv.x * W4s[4 * k4] + xv.y * W4s[4 * k4 + 1]
           + xv.z * W4s[4 * k4 + 2] + xv.w * W4s[4 * k4 + 3];
    }
    hv[n] = a;
}

// ---------------- aggregation (gather, float4, 8 lanes per node) ----------------

__global__ void agg32v(const float* __restrict__ h, const int* __restrict__ off,
                       const int* __restrict__ eby, const float* __restrict__ dinv,
                       const float* __restrict__ b, float* __restrict__ xc, int colOff, int N) {
    int idx = blockIdx.x * 256 + threadIdx.x;
    int n = idx >> 3, q = idx & 7;       // q: which float4 of the 32-ch row
    if (n >= N) return;
    const float4* h4 = (const float4*)h;
    float dn = dinv[n];
    float4 hv = h4[(size_t)n * 8 + q];
    float4 acc = {hv.x * dn, hv.y * dn, hv.z * dn, hv.w * dn};
    int e0 = off[n], e1 = off[n + 1];
    for (int j = e0; j < e1; ++j) {
        int s = eby[j];
        float ds = dinv[s];
        float4 hs = h4[(size_t)s * 8 + q];
        acc.x += hs.x * ds; acc.y += hs.y * ds; acc.z += hs.z * ds; acc.w += hs.w * ds;
    }
    float4 bb = *(const float4*)&b[q * 4];
    float4 o;
    o.x = tanhf(acc.x * dn + bb.x);
    o.y = tanhf(acc.y * dn + bb.y);
    o.z = tanhf(acc.z * dn + bb.z);
    o.w = tanhf(acc.w * dn + bb.w);
    *(float4*)&xc[(size_t)n * XCS + colOff + q * 4] = o;
}

__global__ void agg1(const float* __restrict__ hv, const int* __restrict__ off,
                     const int* __restrict__ eby, const float* __restrict__ dinv,
                     const float* __restrict__ b4, float* __restrict__ xc, int N) {
    int n = blockIdx.x * 256 + threadIdx.x;
    if (n >= N) return;
    float dn = dinv[n];
    float acc = hv[n] * dn;
    int e0 = off[n], e1 = off[n + 1];
    for (int j = e0; j < e1; ++j) {
        int s = eby[j];
        acc += hv[s] * dinv[s];
    }
    xc[(size_t)n * XCS + 96] = tanhf(acc * dn + b4[0]);
}

// ---------------- fused head ----------------

__global__ void head_kernel(const float* __restrict__ xc,
                            const float* __restrict__ c5w, const float* __restrict__ c5b,
                            const float* __restrict__ c6w, const float* __restrict__ c6b,
                            const float* __restrict__ f1w, const float* __restrict__ f1b,
                            const float* __restrict__ f2w, const float* __restrict__ f2b,
                            float* __restrict__ out) {
    __shared__ float v[NPG];
    __shared__ int   ord[KK];
    __shared__ float topk[KK * FC];
    __shared__ float o5[16 * 30];
    __shared__ float p5[16 * 15];
    __shared__ float z[352];
    __shared__ float h1[128];
    __shared__ float lg[NC];
    __shared__ float lse;

    int g = blockIdx.x;
    int t = threadIdx.x;
    const float* xg = xc + (size_t)g * NPG * XCS;

    if (t < NPG) v[t] = xg[t * XCS + 96];
    __syncthreads();
    if (t < NPG) {
        float vi = v[t];
        int r = 0;
        for (int j = 0; j < NPG; ++j) {
            float vj = v[j];
            r += (vj > vi) || (vj == vi && j < t);  // stable descending rank
        }
        if (r < KK) ord[r] = t;
    }
    __syncthreads();
    for (int i = t; i < KK * FC; i += 128) {
        int r = i / FC, f = i - r * FC;
        topk[i] = xg[ord[r] * XCS + f];
    }
    __syncthreads();
    for (int i = t; i < 16 * 30; i += 128) {
        int ch = i / 30, tt = i - ch * 30;
        float a = c5b[ch];
        const float* w = c5w + ch * FC;
        const float* xx = topk + tt * FC;
        for (int f = 0; f < FC; ++f) a += xx[f] * w[f];
        o5[ch * 30 + tt] = fmaxf(a, 0.f);
    }
    __syncthreads();
    for (int i = t; i < 16 * 15; i += 128) {
        int ch = i / 15, tt = i - ch * 15;
        p5[i] = fmaxf(o5[ch * 30 + 2 * tt], o5[ch * 30 + 2 * tt + 1]);
    }
    __syncthreads();
    for (int i = t; i < 32 * 11; i += 128) {
        int oc = i / 11, tt = i - oc * 11;
        float a = c6b[oc];
#pragma unroll
        for (int ic = 0; ic < 16; ++ic) {
#pragma unroll
            for (int k = 0; k < 5; ++k)
                a += p5[ic * 15 + tt + k] * c6w[oc * 80 + ic * 5 + k];
        }
        z[oc * 11 + tt] = fmaxf(a, 0.f);
    }
    __syncthreads();
    {
        float a = f1b[t];
        for (int i = 0; i < 352; ++i) a += z[i] * f1w[i * 128 + t];
        h1[t] = fmaxf(a, 0.f);
    }
    __syncthreads();
    if (t < NC) {
        float a = f2b[t];
#pragma unroll
        for (int j = 0; j < 128; ++j) a += h1[j] * f2w[j * NC + t];
        lg[t] = a;
    }
    __syncthreads();
    if (t == 0) {
        float m = lg[0];
        for (int c = 1; c < NC; ++c) m = fmaxf(m, lg[c]);
        float s = 0.f;
        for (int c = 0; c < NC; ++c) s += expf(lg[c] - m);
        lse = m + logf(s);
    }
    __syncthreads();
    if (t < NC) out[(size_t)g * NC + t] = lg[t] - lse;
}

// ---------------- launch ----------------

static inline size_t align_up(size_t x, size_t a) { return (x + a - 1) & ~(a - 1); }

extern "C" void kernel_launch(void* const* d_in, const int* in_sizes, int n_in,
                              void* d_out, int out_size, void* d_ws, size_t ws_size,
                              hipStream_t stream) {
    const float* x   = (const float*)d_in[0];
    const int*   ei  = (const int*)d_in[1];
    const float* W1  = (const float*)d_in[3];
    const float* b1  = (const float*)d_in[4];
    const float* W2  = (const float*)d_in[5];
    const float* b2  = (const float*)d_in[6];
    const float* W3  = (const float*)d_in[7];
    const float* b3  = (const float*)d_in[8];
    const float* W4  = (const float*)d_in[9];
    const float* b4  = (const float*)d_in[10];
    const float* c5w = (const float*)d_in[11];
    const float* c5b = (const float*)d_in[12];
    const float* c6w = (const float*)d_in[13];
    const float* c6b = (const float*)d_in[14];
    const float* f1w = (const float*)d_in[15];
    const float* f1b = (const float*)d_in[16];
    const float* f2w = (const float*)d_in[17];
    const float* f2b = (const float*)d_in[18];
    float* out = (float*)d_out;

    const int N = in_sizes[0] / FIN;
    const int E = in_sizes[1] / 2;
    const int G = N / NPG;
    const int NB = (N + 63) >> BKT_SHIFT;   // buckets of 64 nodes
    const int* src = ei;
    const int* dst = ei + E;

    char* ws = (char*)d_ws;
    size_t o = 0;
    int*   cnt  = (int*)(ws + o);  size_t cnt_off = o; o = align_up(o + (size_t)N * 4, 256);
    float* dinv = (float*)(ws + o); o = align_up(o + (size_t)N * 4, 256);
    int*   off  = (int*)(ws + o);  o = align_up(o + (size_t)(N + 1) * 4, 256);
    size_t big = (size_t)(E > N * 32 ? E : N * 32);
    int*   ebuf = (int*)(ws + o);  float* h = (float*)(ws + o);  // union: ebuf dead before h live
    o = align_up(o + big * 4, 256);
    int*   eby  = (int*)(ws + o);  o = align_up(o + (size_t)E * 4, 256);
    float* xcb  = (float*)(ws + o); o = align_up(o + (size_t)N * XCS * 4, 256);
    int*   gcur = (int*)(ws + cnt_off);  // overlay on cnt (dead after scan)
    (void)ws_size;

    hipMemsetAsync(cnt, 0, (size_t)N * 4, stream);

    int gbE  = (E + 255) / 256;
    int gbN  = (N + 255) / 256;
    int gbN8 = ((size_t)N * 8 + 255) / 256;
    int gbN128 = (N + 127) / 128;
    int gbA  = (E + CHA - 1) / CHA;

    count_deg<<<gbE, 256, 0, stream>>>(dst, cnt, E);
    make_dinv<<<gbN, 256, 0, stream>>>(cnt, dinv, N);
    scan_off<<<1, 1024, 0, stream>>>(cnt, off, N);
    init_gcur<<<(NB + 255) / 256, 256, 0, stream>>>(off, gcur, NB);
    bucketA<<<gbA, 256, 0, stream>>>(src, dst, gcur, ebuf, E, NB);
    bucketB<<<NB, 256, 0, stream>>>(ebuf, off, eby, N);

    // layer 1: 128 -> 32
    gemm128_32v<<<gbN128, 256, 0, stream>>>(x, W1, h, N);
    agg32v<<<gbN8, 256, 0, stream>>>(h, off, eby, dinv, b1, xcb, 0, N);
    // layer 2: 32 -> 32
    gemm32_32v<<<gbN128, 256, 0, stream>>>(xcb, 0, W2, h, N);
    agg32v<<<gbN8, 256, 0, stream>>>(h, off, eby, dinv, b2, xcb, 32, N);
    // layer 3: 32 -> 32
    gemm32_32v<<<gbN128, 256, 0, stream>>>(xcb, 32, W3, h, N);
    agg32v<<<gbN8, 256, 0, stream>>>(h, off, eby, dinv, b3, xcb, 64, N);
    // layer 4: 32 -> 1
    gemm32_1<<<gbN, 256, 0, stream>>>(xcb, 64, W4, h, N);
    agg1<<<gbN, 256, 0, stream>>>(h, off, eby, dinv, b4, xcb, N);

    // head
    head_kernel<<<G, 128, 0, stream>>>(xcb, c5w, c5b, c6w, c6b, f1w, f1b, f2w, f2b, out);
}

// Round 3
// 449.625 us; speedup vs baseline: 2.5286x; 1.5933x over previous
//
#include <hip/hip_runtime.h>
#include <hip/hip_bf16.h>
#include <math.h>

// Problem constants (structure of the model; N/E derived at runtime)
#define NPG   100
#define FIN   128
#define KK    30
#define NC    10
#define FC    97    // concat feature width: 32+32+32+1
#define XCS   100   // padded row stride for the concat buffer (16B-aligned rows)

#define BKT_SHIFT 6          // 64 nodes per bucket
#define NBMAX     2048       // supports N up to 131072 (also the src-packing limit 2^17)
#define CHA       8192       // edges per block in bucket pass A
#define BCAP      4096       // LDS-cached edges per bucket in pass B (mean ~2048, 45 sigma)

__device__ inline void fma4(float4& a, float s, const float4& w) {
    a.x += s * w.x; a.y += s * w.y; a.z += s * w.z; a.w += s * w.w;
}

// ---------------- CSR build: two-level bucket sort ----------------
// A1: count edges per 64-node bucket (LDS-aggregated atomics).
// scan_nb: exclusive scan of NB bucket counts (single small block).
// A2: append packed (src | d_local<<17) per bucket, chunk-reserved via gcur.
// B:  per-bucket: LDS-cache segment, per-node count + local scan -> off/dinv,
//     then scatter src ids to final slots (all writes in an ~8KB L2 window).

__global__ void bucket_count(const int* __restrict__ dst, int* __restrict__ bcnt,
                             int E, int NB) {
    __shared__ int hist[NBMAX];
    int t = threadIdx.x;
    int e0 = blockIdx.x * CHA;
    for (int i = t; i < NB; i += 256) hist[i] = 0;
    __syncthreads();
    for (int i = t; i < CHA; i += 256) {
        int e = e0 + i;
        if (e < E) atomicAdd(&hist[dst[e] >> BKT_SHIFT], 1);
    }
    __syncthreads();
    for (int i = t; i < NB; i += 256) {
        int h = hist[i];
        if (h) atomicAdd(&bcnt[i], h);
    }
}

__global__ void scan_nb(const int* __restrict__ bcnt, int* __restrict__ boff,
                        int* __restrict__ gcur, int* __restrict__ off,
                        int NB, int N, int E) {
    __shared__ int ps[256];
    int t = threadIdx.x;
    int chunk = (NB + 255) >> 8;
    int lo = t * chunk; if (lo > NB) lo = NB;
    int hi = lo + chunk; if (hi > NB) hi = NB;
    int s = 0;
    for (int i = lo; i < hi; ++i) s += bcnt[i];
    ps[t] = s;
    __syncthreads();
    for (int d = 1; d < 256; d <<= 1) {
        int v = (t >= d) ? ps[t - d] : 0;
        __syncthreads();
        ps[t] += v;
        __syncthreads();
    }
    int base = (t == 0) ? 0 : ps[t - 1];
    for (int i = lo; i < hi; ++i) { boff[i] = base; gcur[i] = base; base += bcnt[i]; }
    if (t == 255) { boff[NB] = E; off[N] = E; }
}

__global__ void bucketA(const int* __restrict__ src, const int* __restrict__ dst,
                        int* __restrict__ gcur, int* __restrict__ ebuf, int E, int NB) {
    __shared__ int hist[NBMAX];
    __shared__ int base[NBMAX];
    int t = threadIdx.x;
    int e0 = blockIdx.x * CHA;
    for (int i = t; i < NB; i += 256) hist[i] = 0;
    __syncthreads();
    for (int i = t; i < CHA; i += 256) {
        int e = e0 + i;
        if (e < E) atomicAdd(&hist[dst[e] >> BKT_SHIFT], 1);
    }
    __syncthreads();
    for (int i = t; i < NB; i += 256) {
        int h = hist[i];
        base[i] = h ? atomicAdd(&gcur[i], h) : 0;
        hist[i] = 0;
    }
    __syncthreads();
    for (int i = t; i < CHA; i += 256) {
        int e = e0 + i;
        if (e >= E) continue;
        int d = dst[e], b = d >> BKT_SHIFT;
        int r = atomicAdd(&hist[b], 1);
        ebuf[base[b] + r] = src[e] | ((d & 63) << 17);
    }
}

__global__ void bucketB(const int* __restrict__ ebuf, const int* __restrict__ boff,
                        int* __restrict__ eby, int* __restrict__ off,
                        float* __restrict__ dinv, int N) {
    __shared__ int seg[BCAP];
    __shared__ int lcnt[64];
    __shared__ int lcur[64];
    int b = blockIdx.x, t = threadIdx.x;
    int n0 = b << BKT_SHIFT;
    int s = boff[b], e = boff[b + 1];
    int len = e - s;
    if (t < 64) lcnt[t] = 0;
    __syncthreads();
    bool fits = (len <= BCAP);
    if (fits) {
        for (int i = t; i < len; i += 256) {
            int v = ebuf[s + i];
            seg[i] = v;
            atomicAdd(&lcnt[v >> 17], 1);
        }
    } else {
        for (int i = t; i < len; i += 256) atomicAdd(&lcnt[ebuf[s + i] >> 17], 1);
    }
    __syncthreads();
    if (t == 0) {
        int run = s;
        for (int i = 0; i < 64; ++i) { lcur[i] = run; run += lcnt[i]; }
    }
    __syncthreads();
    if (t < 64) {
        int n = n0 + t;
        if (n < N) { off[n] = lcur[t]; dinv[n] = rsqrtf((float)lcnt[t] + 1.0f); }
    }
    __syncthreads();
    if (fits) {
        for (int i = t; i < len; i += 256) {
            int v = seg[i];
            int pos = atomicAdd(&lcur[v >> 17], 1);
            eby[pos] = v & 0x1FFFF;
        }
    } else {
        for (int i = t; i < len; i += 256) {
            int v = ebuf[s + i];
            int pos = atomicAdd(&lcur[v >> 17], 1);
            eby[pos] = v & 0x1FFFF;
        }
    }
}

// ---------------- GEMMs (register-blocked: 4 nodes x 4 ch / thread) ----------------

// h[N][32] = x[N][128] @ W[128][32]
__global__ void gemm128_32v(const float* __restrict__ x, const float* __restrict__ W,
                            float* __restrict__ h, int N) {
    __shared__ float Ws[128 * 32];
    int t = threadIdx.x;
    for (int i = t; i < 128 * 32; i += 256) Ws[i] = W[i];
    __syncthreads();
    int cg = (t & 7) * 4;
    int n0 = blockIdx.x * 128 + (t >> 3) * 4;
    if (n0 >= N) return;
    if (n0 + 4 <= N) {
        const float* xr = x + (size_t)n0 * 128;
        float4 a0 = {0,0,0,0}, a1 = a0, a2 = a0, a3 = a0;
#pragma unroll
        for (int k4 = 0; k4 < 32; ++k4) {
            float4 x0 = *(const float4*)(xr + k4 * 4);
            float4 x1 = *(const float4*)(xr + 128 + k4 * 4);
            float4 x2 = *(const float4*)(xr + 256 + k4 * 4);
            float4 x3 = *(const float4*)(xr + 384 + k4 * 4);
            float4 w0 = *(const float4*)&Ws[(4 * k4 + 0) * 32 + cg];
            float4 w1 = *(const float4*)&Ws[(4 * k4 + 1) * 32 + cg];
            float4 w2 = *(const float4*)&Ws[(4 * k4 + 2) * 32 + cg];
            float4 w3 = *(const float4*)&Ws[(4 * k4 + 3) * 32 + cg];
            fma4(a0, x0.x, w0); fma4(a0, x0.y, w1); fma4(a0, x0.z, w2); fma4(a0, x0.w, w3);
            fma4(a1, x1.x, w0); fma4(a1, x1.y, w1); fma4(a1, x1.z, w2); fma4(a1, x1.w, w3);
            fma4(a2, x2.x, w0); fma4(a2, x2.y, w1); fma4(a2, x2.z, w2); fma4(a2, x2.w, w3);
            fma4(a3, x3.x, w0); fma4(a3, x3.y, w1); fma4(a3, x3.z, w2); fma4(a3, x3.w, w3);
        }
        *(float4*)&h[(size_t)(n0 + 0) * 32 + cg] = a0;
        *(float4*)&h[(size_t)(n0 + 1) * 32 + cg] = a1;
        *(float4*)&h[(size_t)(n0 + 2) * 32 + cg] = a2;
        *(float4*)&h[(size_t)(n0 + 3) * 32 + cg] = a3;
    } else {
        for (int nn = 0; nn < 4; ++nn) {
            int n = n0 + nn; if (n >= N) break;
            float4 a = {0,0,0,0};
            for (int k = 0; k < 128; ++k)
                fma4(a, x[(size_t)n * 128 + k], *(const float4*)&Ws[k * 32 + cg]);
            *(float4*)&h[(size_t)n * 32 + cg] = a;
        }
    }
}

// h[N][32] = xc[:, colOff:colOff+32] @ W[32][32]   (xc row stride XCS)
__global__ void gemm32_32v(const float* __restrict__ xc, int colOff,
                           const float* __restrict__ W, float* __restrict__ h, int N) {
    __shared__ float Ws[32 * 32];
    int t = threadIdx.x;
    for (int i = t; i < 32 * 32; i += 256) Ws[i] = W[i];
    __syncthreads();
    int cg = (t & 7) * 4;
    int n0 = blockIdx.x * 128 + (t >> 3) * 4;
    if (n0 >= N) return;
    if (n0 + 4 <= N) {
        const float* xr = xc + (size_t)n0 * XCS + colOff;
        float4 a0 = {0,0,0,0}, a1 = a0, a2 = a0, a3 = a0;
#pragma unroll
        for (int k4 = 0; k4 < 8; ++k4) {
            float4 x0 = *(const float4*)(xr + k4 * 4);
            float4 x1 = *(const float4*)(xr + XCS + k4 * 4);
            float4 x2 = *(const float4*)(xr + 2 * XCS + k4 * 4);
            float4 x3 = *(const float4*)(xr + 3 * XCS + k4 * 4);
            float4 w0 = *(const float4*)&Ws[(4 * k4 + 0) * 32 + cg];
            float4 w1 = *(const float4*)&Ws[(4 * k4 + 1) * 32 + cg];
            float4 w2 = *(const float4*)&Ws[(4 * k4 + 2) * 32 + cg];
            float4 w3 = *(const float4*)&Ws[(4 * k4 + 3) * 32 + cg];
            fma4(a0, x0.x, w0); fma4(a0, x0.y, w1); fma4(a0, x0.z, w2); fma4(a0, x0.w, w3);
            fma4(a1, x1.x, w0); fma4(a1, x1.y, w1); fma4(a1, x1.z, w2); fma4(a1, x1.w, w3);
            fma4(a2, x2.x, w0); fma4(a2, x2.y, w1); fma4(a2, x2.z, w2); fma4(a2, x2.w, w3);
            fma4(a3, x3.x, w0); fma4(a3, x3.y, w1); fma4(a3, x3.z, w2); fma4(a3, x3.w, w3);
        }
        *(float4*)&h[(size_t)(n0 + 0) * 32 + cg] = a0;
        *(float4*)&h[(size_t)(n0 + 1) * 32 + cg] = a1;
        *(float4*)&h[(size_t)(n0 + 2) * 32 + cg] = a2;
        *(float4*)&h[(size_t)(n0 + 3) * 32 + cg] = a3;
    } else {
        for (int nn = 0; nn < 4; ++nn) {
            int n = n0 + nn; if (n >= N) break;
            float4 a = {0,0,0,0};
            for (int k = 0; k < 32; ++k)
                fma4(a, xc[(size_t)n * XCS + colOff + k], *(const float4*)&Ws[k * 32 + cg]);
            *(float4*)&h[(size_t)n * 32 + cg] = a;
        }
    }
}

// hv[N] = xc[:, colOff:colOff+32] @ W4[32]
__global__ void gemm32_1(const float* __restrict__ xc, int colOff,
                         const float* __restrict__ W4, float* __restrict__ hv, int N) {
    __shared__ float W4s[32];
    int t = threadIdx.x;
    if (t < 32) W4s[t] = W4[t];
    __syncthreads();
    int n = blockIdx.x * 256 + t;
    if (n >= N) return;
    const float* xr = xc + (size_t)n * XCS + colOff;
    float a = 0.f;
#pragma unroll
    for (int k4 = 0; k4 < 8; ++k4) {
        float4 xv = *(const float4*)(xr + k4 * 4);
        a += xv.x * W4s[4 * k4] + xv.y * W4s[4 * k4 + 1]
           + xv.z * W4s[4 * k4 + 2] + xv.w * W4s[4 * k4 + 3];
    }
    hv[n] = a;
}

// ---------------- aggregation (gather, float4, 8 lanes per node) ----------------

__global__ void agg32v(const float* __restrict__ h, const int* __restrict__ off,
                       const int* __restrict__ eby, const float* __restrict__ dinv,
                       const float* __restrict__ b, float* __restrict__ xc, int colOff, int N) {
    int idx = blockIdx.x * 256 + threadIdx.x;
    int n = idx >> 3, q = idx & 7;       // q: which float4 of the 32-ch row
    if (n >= N) return;
    const float4* h4 = (const float4*)h;
    float dn = dinv[n];
    float4 hv = h4[(size_t)n * 8 + q];
    float4 acc = {hv.x * dn, hv.y * dn, hv.z * dn, hv.w * dn};
    int e0 = off[n], e1 = off[n + 1];
    for (int j = e0; j < e1; ++j) {
        int s = eby[j];
        float ds = dinv[s];
        float4 hs = h4[(size_t)s * 8 + q];
        acc.x += hs.x * ds; acc.y += hs.y * ds; acc.z += hs.z * ds; acc.w += hs.w * ds;
    }
    float4 bb = *(const float4*)&b[q * 4];
    float4 o;
    o.x = tanhf(acc.x * dn + bb.x);
    o.y = tanhf(acc.y * dn + bb.y);
    o.z = tanhf(acc.z * dn + bb.z);
    o.w = tanhf(acc.w * dn + bb.w);
    *(float4*)&xc[(size_t)n * XCS + colOff + q * 4] = o;
}

__global__ void agg1(const float* __restrict__ hv, const int* __restrict__ off,
                     const int* __restrict__ eby, const float* __restrict__ dinv,
                     const float* __restrict__ b4, float* __restrict__ xc, int N) {
    int n = blockIdx.x * 256 + threadIdx.x;
    if (n >= N) return;
    float dn = dinv[n];
    float acc = hv[n] * dn;
    int e0 = off[n], e1 = off[n + 1];
    for (int j = e0; j < e1; ++j) {
        int s = eby[j];
        acc += hv[s] * dinv[s];
    }
    xc[(size_t)n * XCS + 96] = tanhf(acc * dn + b4[0]);
}

// ---------------- fused head ----------------

__global__ void head_kernel(const float* __restrict__ xc,
                            const float* __restrict__ c5w, const float* __restrict__ c5b,
                            const float* __restrict__ c6w, const float* __restrict__ c6b,
                            const float* __restrict__ f1w, const float* __restrict__ f1b,
                            const float* __restrict__ f2w, const float* __restrict__ f2b,
                            float* __restrict__ out) {
    __shared__ float v[NPG];
    __shared__ int   ord[KK];
    __shared__ float topk[KK * FC];
    __shared__ float o5[16 * 30];
    __shared__ float p5[16 * 15];
    __shared__ float z[352];
    __shared__ float h1[128];
    __shared__ float lg[NC];
    __shared__ float lse;

    int g = blockIdx.x;
    int t = threadIdx.x;
    const float* xg = xc + (size_t)g * NPG * XCS;

    if (t < NPG) v[t] = xg[t * XCS + 96];
    __syncthreads();
    if (t < NPG) {
        float vi = v[t];
        int r = 0;
        for (int j = 0; j < NPG; ++j) {
            float vj = v[j];
            r += (vj > vi) || (vj == vi && j < t);  // stable descending rank
        }
        if (r < KK) ord[r] = t;
    }
    __syncthreads();
    for (int i = t; i < KK * FC; i += 128) {
        int r = i / FC, f = i - r * FC;
        topk[i] = xg[ord[r] * XCS + f];
    }
    __syncthreads();
    for (int i = t; i < 16 * 30; i += 128) {
        int ch = i / 30, tt = i - ch * 30;
        float a = c5b[ch];
        const float* w = c5w + ch * FC;
        const float* xx = topk + tt * FC;
        for (int f = 0; f < FC; ++f) a += xx[f] * w[f];
        o5[ch * 30 + tt] = fmaxf(a, 0.f);
    }
    __syncthreads();
    for (int i = t; i < 16 * 15; i += 128) {
        int ch = i / 15, tt = i - ch * 15;
        p5[i] = fmaxf(o5[ch * 30 + 2 * tt], o5[ch * 30 + 2 * tt + 1]);
    }
    __syncthreads();
    for (int i = t; i < 32 * 11; i += 128) {
        int oc = i / 11, tt = i - oc * 11;
        float a = c6b[oc];
#pragma unroll
        for (int ic = 0; ic < 16; ++ic) {
#pragma unroll
            for (int k = 0; k < 5; ++k)
                a += p5[ic * 15 + tt + k] * c6w[oc * 80 + ic * 5 + k];
        }
        z[oc * 11 + tt] = fmaxf(a, 0.f);
    }
    __syncthreads();
    {
        float a = f1b[t];
        for (int i = 0; i < 352; ++i) a += z[i] * f1w[i * 128 + t];
        h1[t] = fmaxf(a, 0.f);
    }
    __syncthreads();
    if (t < NC) {
        float a = f2b[t];
#pragma unroll
        for (int j = 0; j < 128; ++j) a += h1[j] * f2w[j * NC + t];
        lg[t] = a;
    }
    __syncthreads();
    if (t == 0) {
        float m = lg[0];
        for (int c = 1; c < NC; ++c) m = fmaxf(m, lg[c]);
        float s = 0.f;
        for (int c = 0; c < NC; ++c) s += expf(lg[c] - m);
        lse = m + logf(s);
    }
    __syncthreads();
    if (t < NC) out[(size_t)g * NC + t] = lg[t] - lse;
}

// ---------------- launch ----------------

static inline size_t align_up(size_t x, size_t a) { return (x + a - 1) & ~(a - 1); }

extern "C" void kernel_launch(void* const* d_in, const int* in_sizes, int n_in,
                              void* d_out, int out_size, void* d_ws, size_t ws_size,
                              hipStream_t stream) {
    const float* x   = (const float*)d_in[0];
    const int*   ei  = (const int*)d_in[1];
    const float* W1  = (const float*)d_in[3];
    const float* b1  = (const float*)d_in[4];
    const float* W2  = (const float*)d_in[5];
    const float* b2  = (const float*)d_in[6];
    const float* W3  = (const float*)d_in[7];
    const float* b3  = (const float*)d_in[8];
    const float* W4  = (const float*)d_in[9];
    const float* b4  = (const float*)d_in[10];
    const float* c5w = (const float*)d_in[11];
    const float* c5b = (const float*)d_in[12];
    const float* c6w = (const float*)d_in[13];
    const float* c6b = (const float*)d_in[14];
    const float* f1w = (const float*)d_in[15];
    const float* f1b = (const float*)d_in[16];
    const float* f2w = (const float*)d_in[17];
    const float* f2b = (const float*)d_in[18];
    float* out = (float*)d_out;

    const int N = in_sizes[0] / FIN;
    const int E = in_sizes[1] / 2;
    const int G = N / NPG;
    const int NB = (N + 63) >> BKT_SHIFT;   // buckets of 64 nodes
    const int* src = ei;
    const int* dst = ei + E;

    char* ws = (char*)d_ws;
    size_t o = 0;
    int*   bcnt = (int*)(ws + o);  o = align_up(o + (size_t)NB * 4, 256);
    int*   boff = (int*)(ws + o);  o = align_up(o + (size_t)(NB + 1) * 4, 256);
    int*   gcur = (int*)(ws + o);  o = align_up(o + (size_t)NB * 4, 256);
    float* dinv = (float*)(ws + o); o = align_up(o + (size_t)N * 4, 256);
    int*   off  = (int*)(ws + o);  o = align_up(o + (size_t)(N + 1) * 4, 256);
    size_t big = (size_t)(E > N * 32 ? E : N * 32);
    int*   ebuf = (int*)(ws + o);  float* h = (float*)(ws + o);  // union: ebuf dead before h live
    o = align_up(o + big * 4, 256);
    int*   eby  = (int*)(ws + o);  o = align_up(o + (size_t)E * 4, 256);
    float* xcb  = (float*)(ws + o); o = align_up(o + (size_t)N * XCS * 4, 256);
    (void)ws_size;

    hipMemsetAsync(bcnt, 0, (size_t)NB * 4, stream);

    int gbN  = (N + 255) / 256;
    int gbN8 = ((size_t)N * 8 + 255) / 256;
    int gbN128 = (N + 127) / 128;
    int gbA  = (E + CHA - 1) / CHA;

    bucket_count<<<gbA, 256, 0, stream>>>(dst, bcnt, E, NB);
    scan_nb<<<1, 256, 0, stream>>>(bcnt, boff, gcur, off, NB, N, E);
    bucketA<<<gbA, 256, 0, stream>>>(src, dst, gcur, ebuf, E, NB);
    bucketB<<<NB, 256, 0, stream>>>(ebuf, boff, eby, off, dinv, N);

    // layer 1: 128 -> 32
    gemm128_32v<<<gbN128, 256, 0, stream>>>(x, W1, h, N);
    agg32v<<<gbN8, 256, 0, stream>>>(h, off, eby, dinv, b1, xcb, 0, N);
    // layer 2: 32 -> 32
    gemm32_32v<<<gbN128, 256, 0, stream>>>(xcb, 0, W2, h, N);
    agg32v<<<gbN8, 256, 0, stream>>>(h, off, eby, dinv, b2, xcb, 32, N);
    // layer 3: 32 -> 32
    gemm32_32v<<<gbN128, 256, 0, stream>>>(xcb, 32, W3, h, N);
    agg32v<<<gbN8, 256, 0, stream>>>(h, off, eby, dinv, b3, xcb, 64, N);
    // layer 4: 32 -> 1
    gemm32_1<<<gbN, 256, 0, stream>>>(xcb, 64, W4, h, N);
    agg1<<<gbN, 256, 0, stream>>>(h, off, eby, dinv, b4, xcb, N);

    // head
    head_kernel<<<G, 128, 0, stream>>>(xcb, c5w, c5b, c6w, c6b, f1w, f1b, f2w, f2b, out);
}